// Round 3
// baseline (10.991 us; speedup 1.0000x reference)
//
#include <hip/hip_runtime.h>

// TransitionLayer: N=16, M=64, R=2, B=4096, E=256.
// Only 32 of 256 e-values survive the mask (diag + superdiag wrap); row softmax
// collapses to p = Gd^2/(Gd^2+Gn^2); selector softmax collapses to L = a + b*u
// with a=(w0+w2), b=(w1-w2), batch-independent.
//
// One kernel, 256 blocks x 1024 threads, 16 batches/block.
// thread = (ke = tid>>5, lb = (tid>>1)&15, half = tid&1); each half does 32 of
// the 64 m-iterations; halves combine via shfl_xor(1); the (diag,next) G pair
// exchanges via shfl_xor(32). 2 barriers total. All divisions -> v_rcp_f32.

#define AB_STRIDE 260   // dwords per ke row (64 float4 + 16B pad), 1040 B
#define U_STRIDE  65    // dwords per u row: bank=(lb+m)%32 -> 2-way alias, free

__global__ __launch_bounds__(1024) void fused_kernel(
    const float* __restrict__ u_t, const float* __restrict__ sel,
    const float* __restrict__ alog, float* __restrict__ out) {
  __shared__ float ab4[32 * AB_STRIDE];   // [ke][m] float4 = (a0,b0,a1,b1)
  __shared__ float u_s[16 * U_STRIDE];    // [lb][m], scalar-staged
  __shared__ float alpha_s[64];           // [ke*2 + r]
  __shared__ float ps[16][33];

  const int tid = threadIdx.x;
  const int bid = blockIdx.x;

  // ---- stage u: 1024 floats, 1 scalar coalesced load/thread ----
  {
    float v = u_t[(size_t)bid * 1024 + tid];
    int row = tid >> 6, j = tid & 63;
    u_s[row * U_STRIDE + j] = v;
  }

  // ---- (a,b) table: 4096 entries, 4 per thread ----
  #pragma unroll
  for (int k = 0; k < 4; ++k) {
    int idx = k * 1024 + tid;            // ((ke*2+r)*64 + m)
    int m  = idx & 63;
    int r  = (idx >> 6) & 1;
    int ke = idx >> 7;
    int q   = ke >> 1;
    int col = (q + (ke & 1)) & 15;
    int e   = q * 16 + col;
    const float* s = sel + (size_t)((e * 2 + r) * 64 + m) * 3;
    // softmax over 3 at temp 0.8; |1.25*s| small -> skip max subtraction
    float e0 = __expf(s[0] * 1.25f);
    float e1 = __expf(s[1] * 1.25f);
    float e2 = __expf(s[2] * 1.25f);
    float inv = __builtin_amdgcn_rcpf(e0 + e1 + e2);
    float a = (e0 + e2) * inv;
    float b = (e1 - e2) * inv;
    *(float2*)&ab4[ke * AB_STRIDE + m * 4 + r * 2] = make_float2(a, b);
  }

  // ---- alpha = sigmoid(alog) for the 64 live (e,r) ----
  if (tid < 64) {
    int ke = tid >> 1, r = tid & 1;
    int q = ke >> 1, col = (q + (ke & 1)) & 15;
    int e = q * 16 + col;
    alpha_s[tid] = __builtin_amdgcn_rcpf(1.0f + __expf(-alog[e * 2 + r]));
  }
  __syncthreads();

  // ---- main: thread = (ke, lb, half); 32 m's each, 4 independent chains ----
  const int half = tid & 1;
  const int lb   = (tid >> 1) & 15;
  const int ke   = tid >> 5;            // 2 distinct ke per wave -> broadcast
  const float* uu    = &u_s[lb * U_STRIDE + half * 32];
  const float* abrow = &ab4[ke * AB_STRIDE + half * 128];

  float c0a = 1.0f, c0b = 1.0f, c1a = 1.0f, c1b = 1.0f;
  #pragma unroll
  for (int i = 0; i < 32; i += 2) {
    float4 w0 = *(const float4*)(abrow + i * 4);
    float4 w1 = *(const float4*)(abrow + i * 4 + 4);
    float ua = uu[i], ub = uu[i + 1];
    c0a *= fminf(fmaxf(fmaf(w0.y, ua, w0.x), 0.0f), 1.0f);
    c1a *= fminf(fmaxf(fmaf(w0.w, ua, w0.z), 0.0f), 1.0f);
    c0b *= fminf(fmaxf(fmaf(w1.y, ub, w1.x), 0.0f), 1.0f);
    c1b *= fminf(fmaxf(fmaf(w1.w, ub, w1.z), 0.0f), 1.0f);
  }
  float C0 = c0a * c0b, C1 = c1a * c1b;
  float o0 = __shfl_xor(C0, 1, 64);     // partner half's product
  float o1 = __shfl_xor(C1, 1, 64);
  C0 *= o0;
  C1 *= o1;

  float z0 = fminf(fmaxf(alpha_s[ke * 2]     * C0, 0.0f), 1.0f);
  float z1 = fminf(fmaxf(alpha_s[ke * 2 + 1] * C1, 0.0f), 1.0f);
  float g  = 1.0f - (1.0f - z0) * (1.0f - z1);
  float Gc = fmaxf(g, 1e-6f);
  float Go = __shfl_xor(Gc, 32, 64);    // (ke^1, lb) partner
  float x2 = Gc * Gc, y2 = Go * Go;
  float p  = x2 * __builtin_amdgcn_rcpf(x2 + y2);  // 2-way softmax @ temp 0.5
  if (half == 0) ps[lb][ke] = p;
  __syncthreads();

  // ---- write 16 batches x 256 floats: 1 float4/thread, fully coalesced ----
  {
    int bl  = tid >> 6;          // local batch
    int rem = tid & 63;          // float4 within the 256-float row-block
    int q   = rem >> 2;          // output row
    int c0  = (rem & 3) * 4;     // first col of this float4
    int nq  = (q + 1) & 15;
    float pd = ps[bl][2 * q], pn = ps[bl][2 * q + 1];
    float4 v;
    float* vp = (float*)&v;
    #pragma unroll
    for (int c = 0; c < 4; ++c) {
      int col = c0 + c;
      vp[c] = (col == q) ? pd : (col == nq) ? pn : 0.0f;
    }
    ((float4*)(out + (size_t)bid * 4096))[tid] = v;
  }
}

extern "C" void kernel_launch(void* const* d_in, const int* in_sizes, int n_in,
                              void* d_out, int out_size, void* d_ws, size_t ws_size,
                              hipStream_t stream) {
  const float* u_t  = (const float*)d_in[0];
  const float* sel  = (const float*)d_in[1];
  const float* alog = (const float*)d_in[2];
  float* out = (float*)d_out;
  fused_kernel<<<256, 1024, 0, stream>>>(u_t, sel, alog, out);
}

// Round 4
// 10.061 us; speedup vs baseline: 1.0924x; 1.0924x over previous
//
#include <hip/hip_runtime.h>

// TransitionLayer: N=16, M=64, R=2, B=4096, E=256.
// Only 32 of 256 e-values survive the mask (diag + superdiag wrap); row softmax
// collapses to p = Gd^2/(Gd^2+Gn^2); selector softmax collapses to L = a + b*u
// with a=(w0+w2), b=(w1-w2), batch-independent.
//
// One kernel, 256 blocks x 512 threads, 16 batches/block.
// thread = (ke = tid>>4, lb = tid&15). Wave has 4 distinct ke -> ab reads are
// 16-lane-broadcast ds_read_b128 (bank-quad staggered, conflict-free).
// G pair (diag,next) exchanged via shfl_xor(16) -> only 2 barriers.

#define AB_STRIDE 260   // dwords per ke row (64 float4 + 16B pad), 1040 B
#define U_STRIDE  66    // dwords per u row; bank=(2*lb+m)%32 -> 16 distinct

__global__ __launch_bounds__(512) void fused_kernel(
    const float* __restrict__ u_t, const float* __restrict__ sel,
    const float* __restrict__ alog, float* __restrict__ out) {
  __shared__ float ab4[32 * AB_STRIDE];   // [ke][m] float4 = (a0,b0,a1,b1)
  __shared__ float u_s[16 * U_STRIDE];    // [lb][m]
  __shared__ float alpha_s[64];           // [ke*2 + r]
  __shared__ float ps[16][33];

  const int tid = threadIdx.x;
  const int bid = blockIdx.x;

  // ---- stage u: 1024 floats, one float2 per thread ----
  {
    float2 v = *(const float2*)(u_t + (size_t)bid * 1024 + tid * 2);
    int row = tid >> 5, j = (tid & 31) * 2;
    *(float2*)&u_s[row * U_STRIDE + j] = v;
  }

  // ---- (a,b) table: 4096 entries, 8 per thread ----
  #pragma unroll
  for (int k = 0; k < 8; ++k) {
    int idx = k * 512 + tid;            // ((ke*2+r)*64 + m)
    int m  = idx & 63;
    int r  = (idx >> 6) & 1;
    int ke = idx >> 7;
    int q   = ke >> 1;
    int col = (q + (ke & 1)) & 15;
    int e   = q * 16 + col;
    const float* s = sel + (size_t)((e * 2 + r) * 64 + m) * 3;
    // softmax over 3 at temp 0.8; |1.25*s| <~ 4 -> skip max subtraction
    float e0 = __expf(s[0] * 1.25f);
    float e1 = __expf(s[1] * 1.25f);
    float e2 = __expf(s[2] * 1.25f);
    float inv = __builtin_amdgcn_rcpf(e0 + e1 + e2);
    float a = (e0 + e2) * inv;
    float b = (e1 - e2) * inv;
    *(float2*)&ab4[ke * AB_STRIDE + m * 4 + r * 2] = make_float2(a, b);
  }

  // ---- alpha = sigmoid(alog) for the 64 live (e,r) ----
  if (tid < 64) {
    int ke = tid >> 1, r = tid & 1;
    int q = ke >> 1, col = (q + (ke & 1)) & 15;
    int e = q * 16 + col;
    alpha_s[tid] = __builtin_amdgcn_rcpf(1.0f + __expf(-alog[e * 2 + r]));
  }
  __syncthreads();

  // ---- main: thread = (ke, lb); 64 m's, 4 independent product chains ----
  const int ke = tid >> 4;     // 4 distinct per wave -> broadcast reads
  const int lb = tid & 15;
  const float* uu    = &u_s[lb * U_STRIDE];
  const float* abrow = &ab4[ke * AB_STRIDE];

  float c0a = 1.0f, c0b = 1.0f, c1a = 1.0f, c1b = 1.0f;
  #pragma unroll 8
  for (int i = 0; i < 64; i += 2) {
    float4 w0 = *(const float4*)(abrow + i * 4);
    float4 w1 = *(const float4*)(abrow + i * 4 + 4);
    float ua = uu[i], ub = uu[i + 1];
    c0a *= fminf(fmaxf(fmaf(w0.y, ua, w0.x), 0.0f), 1.0f);
    c1a *= fminf(fmaxf(fmaf(w0.w, ua, w0.z), 0.0f), 1.0f);
    c0b *= fminf(fmaxf(fmaf(w1.y, ub, w1.x), 0.0f), 1.0f);
    c1b *= fminf(fmaxf(fmaf(w1.w, ub, w1.z), 0.0f), 1.0f);
  }
  float C0 = c0a * c0b;
  float C1 = c1a * c1b;

  float z0 = fminf(fmaxf(alpha_s[ke * 2]     * C0, 0.0f), 1.0f);
  float z1 = fminf(fmaxf(alpha_s[ke * 2 + 1] * C1, 0.0f), 1.0f);
  float g  = 1.0f - (1.0f - z0) * (1.0f - z1);
  float Gc = fmaxf(g, 1e-6f);
  float Go = __shfl_xor(Gc, 16, 64);    // partner (ke^1, lb), same wave
  float x2 = Gc * Gc, y2 = Go * Go;
  float p  = x2 * __builtin_amdgcn_rcpf(x2 + y2);  // 2-way softmax @ temp 0.5
  ps[lb][ke] = p;
  __syncthreads();

  // ---- write 16 batches x 256 floats: 2 float4/thread, fully coalesced ----
  float4* obase = (float4*)(out + (size_t)bid * 4096);
  #pragma unroll
  for (int j = 0; j < 2; ++j) {
    int idx = j * 512 + tid;     // float4 index within block tile
    int bl  = idx >> 6;          // local batch
    int rem = idx & 63;          // float4 within the 256-float row-block
    int q   = rem >> 2;          // output row
    int c0  = (rem & 3) * 4;     // first col of this float4
    int nq  = (q + 1) & 15;
    float pd = ps[bl][2 * q], pn = ps[bl][2 * q + 1];
    float4 v;
    float* vp = (float*)&v;
    #pragma unroll
    for (int c = 0; c < 4; ++c) {
      int col = c0 + c;
      vp[c] = (col == q) ? pd : (col == nq) ? pn : 0.0f;
    }
    obase[idx] = v;
  }
}

extern "C" void kernel_launch(void* const* d_in, const int* in_sizes, int n_in,
                              void* d_out, int out_size, void* d_ws, size_t ws_size,
                              hipStream_t stream) {
  const float* u_t  = (const float*)d_in[0];
  const float* sel  = (const float*)d_in[1];
  const float* alog = (const float*)d_in[2];
  float* out = (float*)d_out;
  fused_kernel<<<256, 512, 0, stream>>>(u_t, sel, alog, out);
}